// Round 2
// baseline (760.027 us; speedup 1.0000x reference)
//
#include <hip/hip_runtime.h>
#include <hip/hip_bf16.h>

#define N_NODES 100000
#define N_EDGES 3200000
#define FIN 512
#define FOUT 256
#define GEMM_BM 128
#define GEMM_BN 128
#define GEMM_BK 32

// partition sort params: 128 dest-nodes per partition
#define NP 782                 // ceil(100000/128)
#define CAP_LDS 4608           // max records staged per partition (mean 4096, sd 64 -> 8 sigma)
#define SC_CHUNK 16384         // edges per part_scatter block

typedef __attribute__((ext_vector_type(8))) short short8;
typedef __attribute__((ext_vector_type(4))) float f32x4;

__device__ __forceinline__ unsigned short f2bf(float f) {
    unsigned u = __float_as_uint(f);
    u += 0x7fffu + ((u >> 16) & 1u);      // RNE to bf16
    return (unsigned short)(u >> 16);
}
__device__ __forceinline__ float bf2f(unsigned short h) {
    return __uint_as_float(((unsigned)h) << 16);
}

// direct-to-LDS 16B async copy (lds dest must be wave-uniform; HW adds lane*16)
__device__ __forceinline__ void gload_lds16(const void* g, void* l) {
    __builtin_amdgcn_global_load_lds(
        (const __attribute__((address_space(1))) unsigned*)g,
        (__attribute__((address_space(3))) unsigned*)l, 16, 0, 0);
}

// ---------------------------------------------------------------------------
// Kernel 1: W [512][256] fp32 -> Wt bf16, stored as per-(K-step, N-tile) 8KB
// chunks that are LDS-image-linear for global_load_lds, with the ds_read
// bank-conflict XOR swizzle baked in:
//   chunk(s, nt) covers k in [32s,32s+32), n in [128nt, 128nt+128)
//   within chunk: short offset = nl*32 + u*8 + (k&7),
//   u = (k>>3 of the 32-k block) ^ (nl&3) ^ ((nl>>2)&3)   (bijective)
// ---------------------------------------------------------------------------
__global__ __launch_bounds__(256) void prep_weight(const float* __restrict__ W,
                                                   unsigned short* __restrict__ Wt) {
    int idx = blockIdx.x * 256 + threadIdx.x;
    if (idx < FIN * FOUT) {
        int k = idx >> 8;        // 0..511
        int n = idx & 255;       // 0..255
        int s = k >> 5;          // K-step
        int kk = k & 31;
        int nt = n >> 7;         // N-tile
        int nl = n & 127;
        int kb16 = kk >> 3;      // which 16B unit (8 shorts) of the 64B row
        int u = kb16 ^ (nl & 3) ^ ((nl >> 2) & 3);
        Wt[(size_t)((s * 2 + nt) << 12) + nl * 32 + u * 8 + (kk & 7)] = f2bf(W[idx]);
    }
}

// ---------------------------------------------------------------------------
// Kernel 2: support(bf16) = bf16(X @ W). m93/m97-shape: 256 threads = 4 waves,
// BM=128 x BN=128 x BK=32; wave (wm,wn) owns rows [64wm,+64) x cols [64wn,+64).
// A: fp32 global -> regs -> bf16 -> padded LDS (proven fragment path).
// B: global_load_lds width=16 into linear LDS (pre-swizzled Wt), XOR-undone
// on the ds_read_b128 side (2-way max bank aliasing = free).
// No min-waves launch-bound clamp: the old (512,4) capped VGPR at 128 with a
// ~130-reg live set -> suspected K-loop accumulator spills.
// ---------------------------------------------------------------------------
__global__ __launch_bounds__(256)
void gemm_kernel(const float* __restrict__ X, const unsigned short* __restrict__ Wt,
                 unsigned short* __restrict__ support) {
    __shared__ unsigned short A_lds[GEMM_BM][40];          // 10 KB, pad 40 (proven)
    __shared__ __align__(16) unsigned short bls[4096];     // 8 KB, B chunk image

    const int t = threadIdx.x;
    const int lane = t & 63;
    const int w = t >> 6;         // 0..3
    const int wm = w >> 1;        // 0..1  (M half)
    const int wn = w & 1;         // 0..1  (N half)
    const int q = lane >> 4;
    const int lr = lane & 15;
    const int m0 = blockIdx.x * GEMM_BM;
    const int nt = blockIdx.y;    // 0..1

    f32x4 acc[4][4];
#pragma unroll
    for (int i = 0; i < 4; i++)
#pragma unroll
        for (int j = 0; j < 4; j++) acc[i][j] = (f32x4)0.0f;

    const int arow = t >> 1;            // 0..127, 2 threads per A row
    const int acol = (t & 1) * 16;      // 16 fp32 each
    const bool avalid = (m0 + arow) < N_NODES;
    const float* Xp = X + (size_t)(m0 + arow) * FIN + acol;

    // B global source: chunk(s,nt) is contiguous 8KB; thread t carries 16B at t*16
    const unsigned short* gB = Wt + ((size_t)nt << 12) + t * 8;
    unsigned short* ldsB0 = &bls[w * 512];            // wave-uniform dest, issue 0
    unsigned short* ldsB1 = &bls[2048 + w * 512];     // wave-uniform dest, issue 1

    for (int s = 0; s < FIN / GEMM_BK; ++s) {
        // ---- A tile: global fp32 -> regs -> bf16 (overlaps prior MFMA) ----
        union { __hip_bfloat162 h[8]; uint4 v[2]; } pk;
        if (avalid) {
            float4 v0 = *(const float4*)(Xp + s * GEMM_BK);
            float4 v1 = *(const float4*)(Xp + s * GEMM_BK + 4);
            float4 v2 = *(const float4*)(Xp + s * GEMM_BK + 8);
            float4 v3 = *(const float4*)(Xp + s * GEMM_BK + 12);
            pk.h[0] = __float22bfloat162_rn(make_float2(v0.x, v0.y));
            pk.h[1] = __float22bfloat162_rn(make_float2(v0.z, v0.w));
            pk.h[2] = __float22bfloat162_rn(make_float2(v1.x, v1.y));
            pk.h[3] = __float22bfloat162_rn(make_float2(v1.z, v1.w));
            pk.h[4] = __float22bfloat162_rn(make_float2(v2.x, v2.y));
            pk.h[5] = __float22bfloat162_rn(make_float2(v2.z, v2.w));
            pk.h[6] = __float22bfloat162_rn(make_float2(v3.x, v3.y));
            pk.h[7] = __float22bfloat162_rn(make_float2(v3.z, v3.w));
        } else {
            pk.v[0] = make_uint4(0, 0, 0, 0);
            pk.v[1] = make_uint4(0, 0, 0, 0);
        }

        __syncthreads();   // protect prior iteration's fragment reads

        // ---- B tile: 8KB direct to LDS (2 x 4KB issues), no reg roundtrip ----
        gload_lds16(gB + (size_t)s * 8192, ldsB0);
        gload_lds16(gB + (size_t)s * 8192 + 2048, ldsB1);

        *(uint4*)&A_lds[arow][acol] = pk.v[0];
        *(uint4*)&A_lds[arow][acol + 8] = pk.v[1];

        __syncthreads();   // compiler drains vmcnt(0)+lgkmcnt(0) here: B+A ready

        short8 af[4], bfr[4];
#pragma unroll
        for (int i = 0; i < 4; i++) af[i] = *(const short8*)&A_lds[wm * 64 + i * 16 + lr][q * 8];
#pragma unroll
        for (int j = 0; j < 4; j++) {
            int nl = wn * 64 + j * 16 + lr;
            int u = q ^ (nl & 3) ^ ((nl >> 2) & 3);   // undo the baked swizzle
            bfr[j] = *(const short8*)&bls[nl * 32 + u * 8];
        }
#pragma unroll
        for (int i = 0; i < 4; i++)
#pragma unroll
            for (int j = 0; j < 4; j++)
                acc[i][j] = __builtin_amdgcn_mfma_f32_16x16x32_bf16(af[i], bfr[j], acc[i][j], 0, 0, 0);
    }

    const int n0 = nt * GEMM_BN;
#pragma unroll
    for (int i = 0; i < 4; i++) {
#pragma unroll
        for (int r = 0; r < 4; r++) {
            int gm = m0 + wm * 64 + i * 16 + q * 4 + r;
            if (gm < N_NODES) {
#pragma unroll
                for (int j = 0; j < 4; j++)
                    support[(size_t)gm * FOUT + n0 + wn * 64 + j * 16 + lr] = f2bf(acc[i][j][r]);
            }
        }
    }
}

// ---------------------------------------------------------------------------
// Kernel 3: partition histogram (782 bins of 128 nodes), LDS-aggregated
// ---------------------------------------------------------------------------
__global__ __launch_bounds__(256) void part_hist(const int* __restrict__ row,
                                                 unsigned* __restrict__ pcnt) {
    __shared__ unsigned bins[NP];
    for (int i = threadIdx.x; i < NP; i += 256) bins[i] = 0;
    __syncthreads();
    const int e0 = blockIdx.x * 8192;
#pragma unroll
    for (int j = 0; j < 32; ++j) {
        int e = e0 + j * 256 + threadIdx.x;
        if (e < N_EDGES) atomicAdd(&bins[((unsigned)row[e]) >> 7], 1u);
    }
    __syncthreads();
    for (int i = threadIdx.x; i < NP; i += 256)
        if (bins[i]) atomicAdd(&pcnt[i], bins[i]);
}

// ---------------------------------------------------------------------------
// Kernel 4: scan 782 partition counts -> base[] (exclusive), init cursor[]
// ---------------------------------------------------------------------------
__global__ __launch_bounds__(1024) void part_scan(const unsigned* __restrict__ pcnt,
                                                  unsigned* __restrict__ base,
                                                  unsigned* __restrict__ cursor,
                                                  unsigned* __restrict__ row_ptr) {
    __shared__ unsigned s[1024];
    const int t = threadIdx.x;
    unsigned v = (t < NP) ? pcnt[t] : 0u;
    s[t] = v;
    __syncthreads();
#pragma unroll
    for (int off = 1; off < 1024; off <<= 1) {
        unsigned tv = (t >= off) ? s[t - off] : 0u;
        __syncthreads();
        s[t] += tv;
        __syncthreads();
    }
    if (t < NP) {
        unsigned b = s[t] - v;
        base[t] = b;
        cursor[t] = b;
    }
    if (t == 0) {
        base[NP] = N_EDGES;
        row_ptr[N_NODES] = N_EDGES;
    }
}

// ---------------------------------------------------------------------------
// Kernel 5: partition scatter (two LDS-count passes + one range reservation
// per (block, partition); writes land in ~670B runs that merge in L2)
// ---------------------------------------------------------------------------
__global__ __launch_bounds__(256) void part_scatter(const int* __restrict__ row,
                                                    const int* __restrict__ col,
                                                    const float* __restrict__ val,
                                                    unsigned* __restrict__ cursor,
                                                    uint2* __restrict__ part) {
    __shared__ unsigned bins[NP];
    __shared__ unsigned gb[NP];
    for (int i = threadIdx.x; i < NP; i += 256) bins[i] = 0;
    __syncthreads();
    const int e0 = blockIdx.x * SC_CHUNK;
#pragma unroll 4
    for (int j = 0; j < SC_CHUNK / 256; ++j) {
        int e = e0 + j * 256 + threadIdx.x;
        if (e < N_EDGES) atomicAdd(&bins[((unsigned)row[e]) >> 7], 1u);
    }
    __syncthreads();
    for (int i = threadIdx.x; i < NP; i += 256) {
        unsigned c = bins[i];
        gb[i] = c ? atomicAdd(&cursor[i], c) : 0u;
        bins[i] = 0;
    }
    __syncthreads();
#pragma unroll 4
    for (int j = 0; j < SC_CHUNK / 256; ++j) {
        int e = e0 + j * 256 + threadIdx.x;
        if (e < N_EDGES) {
            unsigned r = (unsigned)row[e];
            unsigned p = r >> 7;
            unsigned l = atomicAdd(&bins[p], 1u);
            part[gb[p] + l] = make_uint2(((unsigned)col[e]) | ((r & 127u) << 17),
                                         __float_as_uint(val[e]));
        }
    }
}

// ---------------------------------------------------------------------------
// Kernel 6: per-partition finalize: LDS stage + per-node scan + in-place
// scatter; emits row_ptr.
// ---------------------------------------------------------------------------
__global__ __launch_bounds__(256) void part_finalize(const unsigned* __restrict__ base,
                                                     uint2* __restrict__ part,
                                                     unsigned* __restrict__ row_ptr) {
    __shared__ uint2 recs[CAP_LDS];
    __shared__ unsigned ncnt[128], nsc[128], ccur[128];
    const int p = blockIdx.x;
    const int t = threadIdx.x;
    const unsigned b = base[p];
    unsigned cnt = base[p + 1] - b;
    if (cnt > CAP_LDS) cnt = CAP_LDS;   // 8-sigma guard, never taken
    if (t < 128) ncnt[t] = 0;
    __syncthreads();
    for (unsigned i = t; i < cnt; i += 256) {
        uint2 r = part[b + i];
        recs[i] = r;
        atomicAdd(&ncnt[r.x >> 17], 1u);
    }
    __syncthreads();
    if (t < 128) nsc[t] = ncnt[t];
    __syncthreads();
#pragma unroll
    for (int off = 1; off < 128; off <<= 1) {
        unsigned tv = (t < 128 && t >= off) ? nsc[t - off] : 0u;
        __syncthreads();
        if (t < 128) nsc[t] += tv;
        __syncthreads();
    }
    if (t < 128) {
        unsigned ex = nsc[t] - ncnt[t];   // exclusive scan
        ccur[t] = ex;
        int node = p * 128 + t;
        if (node < N_NODES) row_ptr[node] = b + ex;
    }
    __syncthreads();
    for (unsigned i = t; i < cnt; i += 256) {
        uint2 r = recs[i];
        unsigned pos = atomicAdd(&ccur[r.x >> 17], 1u);
        part[b + pos] = make_uint2(r.x & 0x1FFFFu, r.y);
    }
}

// ---------------------------------------------------------------------------
// Kernel 7: SpMM pull. One wave per dest node; lane l owns feats 4l..4l+3.
// Batch deepened 8 -> 16 (16 gathers + 16 record loads in flight per wave;
// ~2 serial latency rounds per node instead of ~4). Prefetch indices proven
// in-bounds: max prefetch idx = start+16*nfull-1 <= end-1.
// ---------------------------------------------------------------------------
__global__ __launch_bounds__(256)
void spmm_kernel(const unsigned* __restrict__ row_ptr, const uint2* __restrict__ sorted,
                 const unsigned short* __restrict__ support, const float* __restrict__ bias,
                 float* __restrict__ out) {
    const int lane = threadIdx.x & 63;
    const int n = blockIdx.x * 4 + (threadIdx.x >> 6);
    const unsigned start = __builtin_amdgcn_readfirstlane(row_ptr[n]);
    const unsigned end   = __builtin_amdgcn_readfirstlane(row_ptr[n + 1]);
    const int fo = lane * 4;
    const unsigned short* sp = support + fo;
    float a0 = 0.f, a1 = 0.f, a2 = 0.f, a3 = 0.f;

    unsigned i = start;
    const unsigned nfull = (end - start) >> 4;
    if (nfull) {
        uint2 e[16];
#pragma unroll
        for (int j = 0; j < 16; ++j) e[j] = sorted[i + j];
        for (unsigned bt = 1; bt < nfull; ++bt) {
            ushort4 s[16];
#pragma unroll
            for (int j = 0; j < 16; ++j) s[j] = *(const ushort4*)(sp + (size_t)e[j].x * FOUT);
            uint2 en[16];
#pragma unroll
            for (int j = 0; j < 16; ++j) en[j] = sorted[i + 16 + j];   // prefetch next batch
#pragma unroll
            for (int j = 0; j < 16; ++j) {
                float v = __uint_as_float(e[j].y);
                a0 += v * bf2f(s[j].x); a1 += v * bf2f(s[j].y);
                a2 += v * bf2f(s[j].z); a3 += v * bf2f(s[j].w);
            }
#pragma unroll
            for (int j = 0; j < 16; ++j) e[j] = en[j];
            i += 16;
        }
        ushort4 s[16];
#pragma unroll
        for (int j = 0; j < 16; ++j) s[j] = *(const ushort4*)(sp + (size_t)e[j].x * FOUT);
#pragma unroll
        for (int j = 0; j < 16; ++j) {
            float v = __uint_as_float(e[j].y);
            a0 += v * bf2f(s[j].x); a1 += v * bf2f(s[j].y);
            a2 += v * bf2f(s[j].z); a3 += v * bf2f(s[j].w);
        }
        i += 16;
    }
    if (end - i >= 8) {
        uint2 e[8];
#pragma unroll
        for (int j = 0; j < 8; ++j) e[j] = sorted[i + j];
        ushort4 s[8];
#pragma unroll
        for (int j = 0; j < 8; ++j) s[j] = *(const ushort4*)(sp + (size_t)e[j].x * FOUT);
#pragma unroll
        for (int j = 0; j < 8; ++j) {
            float v = __uint_as_float(e[j].y);
            a0 += v * bf2f(s[j].x); a1 += v * bf2f(s[j].y);
            a2 += v * bf2f(s[j].z); a3 += v * bf2f(s[j].w);
        }
        i += 8;
    }
    for (; i < end; ++i) {
        uint2 e = sorted[i];
        float v = __uint_as_float(e.y);
        ushort4 s0 = *(const ushort4*)(sp + (size_t)e.x * FOUT);
        a0 += v * bf2f(s0.x); a1 += v * bf2f(s0.y); a2 += v * bf2f(s0.z); a3 += v * bf2f(s0.w);
    }

    float4 bv = *(const float4*)(bias + fo);
    float4 r;
    r.x = rintf(a0 * 1000.f) * 0.001f + bv.x;
    r.y = rintf(a1 * 1000.f) * 0.001f + bv.y;
    r.z = rintf(a2 * 1000.f) * 0.001f + bv.z;
    r.w = rintf(a3 * 1000.f) * 0.001f + bv.w;
    *(float4*)(out + (size_t)n * FOUT + fo) = r;
}

// ---------------------------------------------------------------------------
extern "C" void kernel_launch(void* const* d_in, const int* in_sizes, int n_in,
                              void* d_out, int out_size, void* d_ws, size_t ws_size,
                              hipStream_t stream) {
    (void)in_sizes; (void)n_in; (void)out_size; (void)ws_size;
    const float* X    = (const float*)d_in[0];
    const float* W    = (const float*)d_in[1];
    const float* bias = (const float*)d_in[2];
    const float* eval = (const float*)d_in[3];
    const int*   row  = (const int*)d_in[4];
    const int*   col  = (const int*)d_in[5];
    float* out = (float*)d_out;

    char* p = (char*)d_ws;
    auto take = [&](size_t bytes) {
        char* r = p;
        p += (bytes + 511) & ~(size_t)511;
        return r;
    };
    unsigned short* support = (unsigned short*)take((size_t)N_NODES * FOUT * 2); // 51.2 MB
    unsigned short* Wt      = (unsigned short*)take((size_t)FIN * FOUT * 2);     // 256 KB
    unsigned*       pcnt    = (unsigned*)take((size_t)NP * 4);
    unsigned*       base    = (unsigned*)take((size_t)(NP + 1) * 4);
    unsigned*       cursor  = (unsigned*)take((size_t)NP * 4);
    unsigned*       row_ptr = (unsigned*)take((size_t)(N_NODES + 1) * 4);
    uint2*          part    = (uint2*)take((size_t)N_EDGES * 8 + 1024);          // 25.6 MB + slack

    hipMemsetAsync(pcnt, 0, (size_t)NP * 4, stream);
    prep_weight<<<(FIN * FOUT) / 256, 256, 0, stream>>>(W, Wt);
    gemm_kernel<<<dim3((N_NODES + GEMM_BM - 1) / GEMM_BM, FOUT / GEMM_BN), 256, 0, stream>>>(X, Wt, support);
    part_hist<<<(N_EDGES + 8191) / 8192, 256, 0, stream>>>(row, pcnt);
    part_scan<<<1, 1024, 0, stream>>>(pcnt, base, cursor, row_ptr);
    part_scatter<<<(N_EDGES + SC_CHUNK - 1) / SC_CHUNK, 256, 0, stream>>>(row, col, eval, cursor, part);
    part_finalize<<<NP, 256, 0, stream>>>(base, part, row_ptr);
    spmm_kernel<<<N_NODES / 4, 256, 0, stream>>>(row_ptr, part, support, bias, out);
}

// Round 3
// 705.013 us; speedup vs baseline: 1.0780x; 1.0780x over previous
//
#include <hip/hip_runtime.h>
#include <hip/hip_bf16.h>

#define N_NODES 100000
#define N_EDGES 3200000
#define FIN 512
#define FOUT 256
#define GEMM_BM 128
#define GEMM_BK 32

// partition sort params: 128 dest-nodes per partition
#define NP 782                 // ceil(100000/128)
#define CAP_LDS 4608           // max records staged per partition (mean 4096, sd 64 -> 8 sigma)
#define SC_CHUNK 16384         // edges per part_scatter block

typedef __attribute__((ext_vector_type(8))) short short8;
typedef __attribute__((ext_vector_type(4))) float f32x4;

__device__ __forceinline__ unsigned short f2bf(float f) {
    unsigned u = __float_as_uint(f);
    u += 0x7fffu + ((u >> 16) & 1u);      // RNE to bf16
    return (unsigned short)(u >> 16);
}
__device__ __forceinline__ float bf2f(unsigned short h) {
    return __uint_as_float(((unsigned)h) << 16);
}

// direct-to-LDS 16B async copy (lds dest must be wave-uniform; HW adds lane*16)
__device__ __forceinline__ void gload_lds16(const void* g, void* l) {
    __builtin_amdgcn_global_load_lds(
        (const __attribute__((address_space(1))) unsigned*)g,
        (__attribute__((address_space(3))) unsigned*)l, 16, 0, 0);
}

// ---------------------------------------------------------------------------
// Kernel 1: W [512][256] fp32 -> Wt bf16 as one 16KB chunk per K-step
// (k in [32s,32s+32), all 256 n), LDS-image-linear for global_load_lds with
// the ds_read bank-conflict XOR swizzle baked in:
//   short offset = s*8192 + n*32 + u*8 + (k&7),
//   u = (kk>>3) ^ (n&3) ^ ((n>>2)&3)   (bijective in the 16B-unit index)
// ---------------------------------------------------------------------------
__global__ __launch_bounds__(256) void prep_weight(const float* __restrict__ W,
                                                   unsigned short* __restrict__ Wt) {
    int idx = blockIdx.x * 256 + threadIdx.x;
    if (idx < FIN * FOUT) {
        int k = idx >> 8;        // 0..511
        int n = idx & 255;       // 0..255
        int s = k >> 5;          // K-step
        int kk = k & 31;
        int kb16 = kk >> 3;      // which 16B unit (8 shorts) of the 64B k-row
        int u = kb16 ^ (n & 3) ^ ((n >> 2) & 3);
        Wt[(size_t)s * 8192 + n * 32 + u * 8 + (kk & 7)] = f2bf(W[idx]);
    }
}

// ---------------------------------------------------------------------------
// Kernel 2: support(bf16) = bf16(X @ W). BM=128 x BN=256(full) x BK=32,
// 512 threads = 8 waves; wave (wm,wn) owns rows [64wm,+64) x cols [64wn,+64).
// X is read ONCE (round-2's grid.y split read it twice: -46us regression).
// A: fp32 global -> regs -> bf16 -> padded LDS (round-0-proven fragment path).
// B: global_load_lds width=16 into linear LDS from pre-swizzled Wt; swizzle
// undone on the ds_read_b128 side. B reg-staging eliminated -> live set fits
// without the old (512,4) spill risk; (512,2) lets the allocator breathe.
// ---------------------------------------------------------------------------
__global__ __launch_bounds__(512, 2)
void gemm_kernel(const float* __restrict__ X, const unsigned short* __restrict__ Wt,
                 unsigned short* __restrict__ support) {
    __shared__ unsigned short A_lds[GEMM_BM][40];          // 10 KB, pad 40 (proven)
    __shared__ __align__(16) unsigned short bls[8192];     // 16 KB, B chunk image

    const int t = threadIdx.x;
    const int lane = t & 63;
    const int w = t >> 6;         // 0..7
    const int wm = w >> 2;        // 0..1  (M half)
    const int wn = w & 3;         // 0..3  (N quarter)
    const int q = lane >> 4;
    const int lr = lane & 15;
    const int m0 = blockIdx.x * GEMM_BM;

    f32x4 acc[4][4];
#pragma unroll
    for (int i = 0; i < 4; i++)
#pragma unroll
        for (int j = 0; j < 4; j++) acc[i][j] = (f32x4)0.0f;

    const int arow = t >> 2;            // 0..127, 4 threads per A row
    const int acol = (t & 3) * 8;       // 8 fp32 each
    const bool avalid = (m0 + arow) < N_NODES;
    const float* Xp = X + (size_t)(m0 + arow) * FIN + acol;

    // B global source: chunk s is contiguous 16KB; thread t carries 16B at t*16
    const unsigned short* gB = Wt + t * 8;
    unsigned short* ldsB0 = &bls[w * 512];            // wave-uniform dest, bytes [w*1024,+1024)
    unsigned short* ldsB1 = &bls[4096 + w * 512];     // second 8KB half

    for (int s = 0; s < FIN / GEMM_BK; ++s) {
        // ---- A tile: global fp32 -> regs -> bf16 (overlaps prior MFMA) ----
        union { __hip_bfloat162 h[4]; uint4 v; } pk;
        if (avalid) {
            float4 v0 = *(const float4*)(Xp + s * GEMM_BK);
            float4 v1 = *(const float4*)(Xp + s * GEMM_BK + 4);
            pk.h[0] = __float22bfloat162_rn(make_float2(v0.x, v0.y));
            pk.h[1] = __float22bfloat162_rn(make_float2(v0.z, v0.w));
            pk.h[2] = __float22bfloat162_rn(make_float2(v1.x, v1.y));
            pk.h[3] = __float22bfloat162_rn(make_float2(v1.z, v1.w));
        } else {
            pk.v = make_uint4(0, 0, 0, 0);
        }

        __syncthreads();   // protect prior iteration's fragment reads

        // ---- B tile: 16KB direct to LDS (2 x 8KB issues), no reg roundtrip ----
        gload_lds16(gB + (size_t)s * 8192, ldsB0);
        gload_lds16(gB + (size_t)s * 8192 + 4096, ldsB1);

        *(uint4*)&A_lds[arow][acol] = pk.v;

        __syncthreads();   // compiler drains vmcnt(0)+lgkmcnt(0) here: B+A ready

        short8 af[4], bfr[4];
#pragma unroll
        for (int i = 0; i < 4; i++) af[i] = *(const short8*)&A_lds[wm * 64 + i * 16 + lr][q * 8];
#pragma unroll
        for (int j = 0; j < 4; j++) {
            int nl = wn * 64 + j * 16 + lr;              // 0..255
            int u = q ^ (nl & 3) ^ ((nl >> 2) & 3);      // undo the baked swizzle
            bfr[j] = *(const short8*)&bls[nl * 32 + u * 8];
        }
#pragma unroll
        for (int i = 0; i < 4; i++)
#pragma unroll
            for (int j = 0; j < 4; j++)
                acc[i][j] = __builtin_amdgcn_mfma_f32_16x16x32_bf16(af[i], bfr[j], acc[i][j], 0, 0, 0);
    }

#pragma unroll
    for (int i = 0; i < 4; i++) {
#pragma unroll
        for (int r = 0; r < 4; r++) {
            int gm = m0 + wm * 64 + i * 16 + q * 4 + r;
            if (gm < N_NODES) {
#pragma unroll
                for (int j = 0; j < 4; j++)
                    support[(size_t)gm * FOUT + wn * 64 + j * 16 + lr] = f2bf(acc[i][j][r]);
            }
        }
    }
}

// ---------------------------------------------------------------------------
// Kernel 3: partition histogram (782 bins of 128 nodes), LDS-aggregated
// ---------------------------------------------------------------------------
__global__ __launch_bounds__(256) void part_hist(const int* __restrict__ row,
                                                 unsigned* __restrict__ pcnt) {
    __shared__ unsigned bins[NP];
    for (int i = threadIdx.x; i < NP; i += 256) bins[i] = 0;
    __syncthreads();
    const int e0 = blockIdx.x * 8192;
#pragma unroll
    for (int j = 0; j < 32; ++j) {
        int e = e0 + j * 256 + threadIdx.x;
        if (e < N_EDGES) atomicAdd(&bins[((unsigned)row[e]) >> 7], 1u);
    }
    __syncthreads();
    for (int i = threadIdx.x; i < NP; i += 256)
        if (bins[i]) atomicAdd(&pcnt[i], bins[i]);
}

// ---------------------------------------------------------------------------
// Kernel 4: scan 782 partition counts -> base[] (exclusive), init cursor[]
// ---------------------------------------------------------------------------
__global__ __launch_bounds__(1024) void part_scan(const unsigned* __restrict__ pcnt,
                                                  unsigned* __restrict__ base,
                                                  unsigned* __restrict__ cursor,
                                                  unsigned* __restrict__ row_ptr) {
    __shared__ unsigned s[1024];
    const int t = threadIdx.x;
    unsigned v = (t < NP) ? pcnt[t] : 0u;
    s[t] = v;
    __syncthreads();
#pragma unroll
    for (int off = 1; off < 1024; off <<= 1) {
        unsigned tv = (t >= off) ? s[t - off] : 0u;
        __syncthreads();
        s[t] += tv;
        __syncthreads();
    }
    if (t < NP) {
        unsigned b = s[t] - v;
        base[t] = b;
        cursor[t] = b;
    }
    if (t == 0) {
        base[NP] = N_EDGES;
        row_ptr[N_NODES] = N_EDGES;
    }
}

// ---------------------------------------------------------------------------
// Kernel 5: partition scatter (two LDS-count passes + one range reservation
// per (block, partition); writes land in runs that merge in L2)
// ---------------------------------------------------------------------------
__global__ __launch_bounds__(256) void part_scatter(const int* __restrict__ row,
                                                    const int* __restrict__ col,
                                                    const float* __restrict__ val,
                                                    unsigned* __restrict__ cursor,
                                                    uint2* __restrict__ part) {
    __shared__ unsigned bins[NP];
    __shared__ unsigned gb[NP];
    for (int i = threadIdx.x; i < NP; i += 256) bins[i] = 0;
    __syncthreads();
    const int e0 = blockIdx.x * SC_CHUNK;
#pragma unroll 4
    for (int j = 0; j < SC_CHUNK / 256; ++j) {
        int e = e0 + j * 256 + threadIdx.x;
        if (e < N_EDGES) atomicAdd(&bins[((unsigned)row[e]) >> 7], 1u);
    }
    __syncthreads();
    for (int i = threadIdx.x; i < NP; i += 256) {
        unsigned c = bins[i];
        gb[i] = c ? atomicAdd(&cursor[i], c) : 0u;
        bins[i] = 0;
    }
    __syncthreads();
#pragma unroll 4
    for (int j = 0; j < SC_CHUNK / 256; ++j) {
        int e = e0 + j * 256 + threadIdx.x;
        if (e < N_EDGES) {
            unsigned r = (unsigned)row[e];
            unsigned p = r >> 7;
            unsigned l = atomicAdd(&bins[p], 1u);
            part[gb[p] + l] = make_uint2(((unsigned)col[e]) | ((r & 127u) << 17),
                                         __float_as_uint(val[e]));
        }
    }
}

// ---------------------------------------------------------------------------
// Kernel 6: per-partition finalize: LDS stage + per-node scan + in-place
// scatter; emits row_ptr.
// ---------------------------------------------------------------------------
__global__ __launch_bounds__(256) void part_finalize(const unsigned* __restrict__ base,
                                                     uint2* __restrict__ part,
                                                     unsigned* __restrict__ row_ptr) {
    __shared__ uint2 recs[CAP_LDS];
    __shared__ unsigned ncnt[128], nsc[128], ccur[128];
    const int p = blockIdx.x;
    const int t = threadIdx.x;
    const unsigned b = base[p];
    unsigned cnt = base[p + 1] - b;
    if (cnt > CAP_LDS) cnt = CAP_LDS;   // 8-sigma guard, never taken
    if (t < 128) ncnt[t] = 0;
    __syncthreads();
    for (unsigned i = t; i < cnt; i += 256) {
        uint2 r = part[b + i];
        recs[i] = r;
        atomicAdd(&ncnt[r.x >> 17], 1u);
    }
    __syncthreads();
    if (t < 128) nsc[t] = ncnt[t];
    __syncthreads();
#pragma unroll
    for (int off = 1; off < 128; off <<= 1) {
        unsigned tv = (t < 128 && t >= off) ? nsc[t - off] : 0u;
        __syncthreads();
        if (t < 128) nsc[t] += tv;
        __syncthreads();
    }
    if (t < 128) {
        unsigned ex = nsc[t] - ncnt[t];   // exclusive scan
        ccur[t] = ex;
        int node = p * 128 + t;
        if (node < N_NODES) row_ptr[node] = b + ex;
    }
    __syncthreads();
    for (unsigned i = t; i < cnt; i += 256) {
        uint2 r = recs[i];
        unsigned pos = atomicAdd(&ccur[r.x >> 17], 1u);
        part[b + pos] = make_uint2(r.x & 0x1FFFFu, r.y);
    }
}

// ---------------------------------------------------------------------------
// Kernel 7: SpMM pull, feature-split. grid.y in {0,1} selects 128-feat half;
// lane l owns feats fo..fo+1 (256B gathers). During each y-phase the live
// support working set is 25.6 MB (vs 51.2) -> higher per-XCD L2 hit rate.
// Accumulation order per output feature is identical to before (same edge
// order) -> bit-identical results. Batch 16 retained.
// ---------------------------------------------------------------------------
__global__ __launch_bounds__(256)
void spmm_kernel(const unsigned* __restrict__ row_ptr, const uint2* __restrict__ sorted,
                 const unsigned short* __restrict__ support, const float* __restrict__ bias,
                 float* __restrict__ out) {
    const int lane = threadIdx.x & 63;
    const int n = blockIdx.x * 4 + (threadIdx.x >> 6);
    const unsigned start = __builtin_amdgcn_readfirstlane(row_ptr[n]);
    const unsigned end   = __builtin_amdgcn_readfirstlane(row_ptr[n + 1]);
    const int fo = (blockIdx.y << 7) + lane * 2;
    const unsigned short* sp = support + fo;
    float a0 = 0.f, a1 = 0.f;

    unsigned i = start;
    const unsigned nfull = (end - start) >> 4;
    if (nfull) {
        uint2 e[16];
#pragma unroll
        for (int j = 0; j < 16; ++j) e[j] = sorted[i + j];
        for (unsigned bt = 1; bt < nfull; ++bt) {
            ushort2 s[16];
#pragma unroll
            for (int j = 0; j < 16; ++j) s[j] = *(const ushort2*)(sp + (size_t)e[j].x * FOUT);
            uint2 en[16];
#pragma unroll
            for (int j = 0; j < 16; ++j) en[j] = sorted[i + 16 + j];   // prefetch next batch
#pragma unroll
            for (int j = 0; j < 16; ++j) {
                float v = __uint_as_float(e[j].y);
                a0 += v * bf2f(s[j].x); a1 += v * bf2f(s[j].y);
            }
#pragma unroll
            for (int j = 0; j < 16; ++j) e[j] = en[j];
            i += 16;
        }
        ushort2 s[16];
#pragma unroll
        for (int j = 0; j < 16; ++j) s[j] = *(const ushort2*)(sp + (size_t)e[j].x * FOUT);
#pragma unroll
        for (int j = 0; j < 16; ++j) {
            float v = __uint_as_float(e[j].y);
            a0 += v * bf2f(s[j].x); a1 += v * bf2f(s[j].y);
        }
        i += 16;
    }
    if (end - i >= 8) {
        uint2 e[8];
#pragma unroll
        for (int j = 0; j < 8; ++j) e[j] = sorted[i + j];
        ushort2 s[8];
#pragma unroll
        for (int j = 0; j < 8; ++j) s[j] = *(const ushort2*)(sp + (size_t)e[j].x * FOUT);
#pragma unroll
        for (int j = 0; j < 8; ++j) {
            float v = __uint_as_float(e[j].y);
            a0 += v * bf2f(s[j].x); a1 += v * bf2f(s[j].y);
        }
        i += 8;
    }
    for (; i < end; ++i) {
        uint2 e = sorted[i];
        float v = __uint_as_float(e.y);
        ushort2 s0 = *(const ushort2*)(sp + (size_t)e.x * FOUT);
        a0 += v * bf2f(s0.x); a1 += v * bf2f(s0.y);
    }

    float2 bv = *(const float2*)(bias + fo);
    float2 r;
    r.x = rintf(a0 * 1000.f) * 0.001f + bv.x;
    r.y = rintf(a1 * 1000.f) * 0.001f + bv.y;
    *(float2*)(out + (size_t)n * FOUT + fo) = r;
}

// ---------------------------------------------------------------------------
extern "C" void kernel_launch(void* const* d_in, const int* in_sizes, int n_in,
                              void* d_out, int out_size, void* d_ws, size_t ws_size,
                              hipStream_t stream) {
    (void)in_sizes; (void)n_in; (void)out_size; (void)ws_size;
    const float* X    = (const float*)d_in[0];
    const float* W    = (const float*)d_in[1];
    const float* bias = (const float*)d_in[2];
    const float* eval = (const float*)d_in[3];
    const int*   row  = (const int*)d_in[4];
    const int*   col  = (const int*)d_in[5];
    float* out = (float*)d_out;

    char* p = (char*)d_ws;
    auto take = [&](size_t bytes) {
        char* r = p;
        p += (bytes + 511) & ~(size_t)511;
        return r;
    };
    unsigned short* support = (unsigned short*)take((size_t)N_NODES * FOUT * 2); // 51.2 MB
    unsigned short* Wt      = (unsigned short*)take((size_t)FIN * FOUT * 2);     // 256 KB
    unsigned*       pcnt    = (unsigned*)take((size_t)NP * 4);
    unsigned*       base    = (unsigned*)take((size_t)(NP + 1) * 4);
    unsigned*       cursor  = (unsigned*)take((size_t)NP * 4);
    unsigned*       row_ptr = (unsigned*)take((size_t)(N_NODES + 1) * 4);
    uint2*          part    = (uint2*)take((size_t)N_EDGES * 8 + 1024);          // 25.6 MB + slack

    hipMemsetAsync(pcnt, 0, (size_t)NP * 4, stream);
    prep_weight<<<(FIN * FOUT) / 256, 256, 0, stream>>>(W, Wt);
    gemm_kernel<<<(N_NODES + GEMM_BM - 1) / GEMM_BM, 512, 0, stream>>>(X, Wt, support);
    part_hist<<<(N_EDGES + 8191) / 8192, 256, 0, stream>>>(row, pcnt);
    part_scan<<<1, 1024, 0, stream>>>(pcnt, base, cursor, row_ptr);
    part_scatter<<<(N_EDGES + SC_CHUNK - 1) / SC_CHUNK, 256, 0, stream>>>(row, col, eval, cursor, part);
    part_finalize<<<NP, 256, 0, stream>>>(base, part, row_ptr);
    spmm_kernel<<<dim3(N_NODES / 4, 2), 256, 0, stream>>>(row_ptr, part, support, bias, out);
}

// Round 4
// 702.624 us; speedup vs baseline: 1.0817x; 1.0034x over previous
//
#include <hip/hip_runtime.h>
#include <hip/hip_bf16.h>

#define N_NODES 100000
#define N_EDGES 3200000
#define FIN 512
#define FOUT 256
#define GEMM_BM 128
#define GEMM_BK 32

// partition sort params: 256 dest-nodes per partition (round-4: was 128;
// doubles scatter run length -> halves partial-line write fragmentation)
#define PSZ 256
#define PSH 8                  // log2(PSZ)
#define NP 391                 // ceil(100000/256)
#define CAP_LDS 8960           // mean 8192, sd 90 -> +8.5 sigma guard
#define SC_CHUNK 16384         // edges per part_scatter block

typedef __attribute__((ext_vector_type(8))) short short8;
typedef __attribute__((ext_vector_type(4))) float f32x4;

__device__ __forceinline__ unsigned short f2bf(float f) {
    unsigned u = __float_as_uint(f);
    u += 0x7fffu + ((u >> 16) & 1u);      // RNE to bf16
    return (unsigned short)(u >> 16);
}
__device__ __forceinline__ float bf2f(unsigned short h) {
    return __uint_as_float(((unsigned)h) << 16);
}

// direct-to-LDS 16B async copy (lds dest must be wave-uniform; HW adds lane*16)
__device__ __forceinline__ void gload_lds16(const void* g, void* l) {
    __builtin_amdgcn_global_load_lds(
        (const __attribute__((address_space(1))) unsigned*)g,
        (__attribute__((address_space(3))) unsigned*)l, 16, 0, 0);
}

// ---------------------------------------------------------------------------
// Kernel 1: W [512][256] fp32 -> Wt bf16 as one 16KB chunk per K-step
// (k in [32s,32s+32), all 256 n), LDS-image-linear for global_load_lds with
// the ds_read bank-conflict XOR swizzle baked in:
//   short offset = s*8192 + n*32 + u*8 + (k&7),
//   u = (kk>>3) ^ (n&3) ^ ((n>>2)&3)   (bijective in the 16B-unit index)
// ---------------------------------------------------------------------------
__global__ __launch_bounds__(256) void prep_weight(const float* __restrict__ W,
                                                   unsigned short* __restrict__ Wt) {
    int idx = blockIdx.x * 256 + threadIdx.x;
    if (idx < FIN * FOUT) {
        int k = idx >> 8;        // 0..511
        int n = idx & 255;       // 0..255
        int s = k >> 5;          // K-step
        int kk = k & 31;
        int kb16 = kk >> 3;      // which 16B unit (8 shorts) of the 64B k-row
        int u = kb16 ^ (n & 3) ^ ((n >> 2) & 3);
        Wt[(size_t)s * 8192 + n * 32 + u * 8 + (kk & 7)] = f2bf(W[idx]);
    }
}

// ---------------------------------------------------------------------------
// Kernel 2: support(bf16) = bf16(X @ W). BM=128 x BN=256(full) x BK=32,
// 512 threads = 8 waves; wave (wm,wn) owns rows [64wm,+64) x cols [64wn,+64).
// X read once (~205MB dominates; measured marginal rate ~4.8TB/s -> ~55us).
// A: fp32 global -> regs -> bf16 -> padded LDS. B: global_load_lds width=16
// from pre-swizzled Wt; swizzle undone on the ds_read_b128 side.
// ---------------------------------------------------------------------------
__global__ __launch_bounds__(512, 2)
void gemm_kernel(const float* __restrict__ X, const unsigned short* __restrict__ Wt,
                 unsigned short* __restrict__ support) {
    __shared__ unsigned short A_lds[GEMM_BM][40];          // 10 KB, pad 40 (proven)
    __shared__ __align__(16) unsigned short bls[8192];     // 16 KB, B chunk image

    const int t = threadIdx.x;
    const int lane = t & 63;
    const int w = t >> 6;         // 0..7
    const int wm = w >> 2;        // 0..1  (M half)
    const int wn = w & 3;         // 0..3  (N quarter)
    const int q = lane >> 4;
    const int lr = lane & 15;
    const int m0 = blockIdx.x * GEMM_BM;

    f32x4 acc[4][4];
#pragma unroll
    for (int i = 0; i < 4; i++)
#pragma unroll
        for (int j = 0; j < 4; j++) acc[i][j] = (f32x4)0.0f;

    const int arow = t >> 2;            // 0..127, 4 threads per A row
    const int acol = (t & 3) * 8;       // 8 fp32 each
    const bool avalid = (m0 + arow) < N_NODES;
    const float* Xp = X + (size_t)(m0 + arow) * FIN + acol;

    // B global source: chunk s is contiguous 16KB; thread t carries 16B at t*16
    const unsigned short* gB = Wt + t * 8;
    unsigned short* ldsB0 = &bls[w * 512];            // wave-uniform dest
    unsigned short* ldsB1 = &bls[4096 + w * 512];     // second 8KB half

    for (int s = 0; s < FIN / GEMM_BK; ++s) {
        // ---- A tile: global fp32 -> regs -> bf16 (overlaps prior MFMA) ----
        union { __hip_bfloat162 h[4]; uint4 v; } pk;
        if (avalid) {
            float4 v0 = *(const float4*)(Xp + s * GEMM_BK);
            float4 v1 = *(const float4*)(Xp + s * GEMM_BK + 4);
            pk.h[0] = __float22bfloat162_rn(make_float2(v0.x, v0.y));
            pk.h[1] = __float22bfloat162_rn(make_float2(v0.z, v0.w));
            pk.h[2] = __float22bfloat162_rn(make_float2(v1.x, v1.y));
            pk.h[3] = __float22bfloat162_rn(make_float2(v1.z, v1.w));
        } else {
            pk.v = make_uint4(0, 0, 0, 0);
        }

        __syncthreads();   // protect prior iteration's fragment reads

        // ---- B tile: 16KB direct to LDS (2 x 8KB issues), no reg roundtrip ----
        gload_lds16(gB + (size_t)s * 8192, ldsB0);
        gload_lds16(gB + (size_t)s * 8192 + 4096, ldsB1);

        *(uint4*)&A_lds[arow][acol] = pk.v;

        __syncthreads();   // compiler drains vmcnt(0)+lgkmcnt(0) here: B+A ready

        short8 af[4], bfr[4];
#pragma unroll
        for (int i = 0; i < 4; i++) af[i] = *(const short8*)&A_lds[wm * 64 + i * 16 + lr][q * 8];
#pragma unroll
        for (int j = 0; j < 4; j++) {
            int nl = wn * 64 + j * 16 + lr;              // 0..255
            int u = q ^ (nl & 3) ^ ((nl >> 2) & 3);      // undo the baked swizzle
            bfr[j] = *(const short8*)&bls[nl * 32 + u * 8];
        }
#pragma unroll
        for (int i = 0; i < 4; i++)
#pragma unroll
            for (int j = 0; j < 4; j++)
                acc[i][j] = __builtin_amdgcn_mfma_f32_16x16x32_bf16(af[i], bfr[j], acc[i][j], 0, 0, 0);
    }

#pragma unroll
    for (int i = 0; i < 4; i++) {
#pragma unroll
        for (int r = 0; r < 4; r++) {
            int gm = m0 + wm * 64 + i * 16 + q * 4 + r;
            if (gm < N_NODES) {
#pragma unroll
                for (int j = 0; j < 4; j++)
                    support[(size_t)gm * FOUT + wn * 64 + j * 16 + lr] = f2bf(acc[i][j][r]);
            }
        }
    }
}

// ---------------------------------------------------------------------------
// Kernel 3: partition histogram (391 bins of 256 nodes), LDS-aggregated
// ---------------------------------------------------------------------------
__global__ __launch_bounds__(256) void part_hist(const int* __restrict__ row,
                                                 unsigned* __restrict__ pcnt) {
    __shared__ unsigned bins[NP];
    for (int i = threadIdx.x; i < NP; i += 256) bins[i] = 0;
    __syncthreads();
    const int e0 = blockIdx.x * 8192;
#pragma unroll
    for (int j = 0; j < 32; ++j) {
        int e = e0 + j * 256 + threadIdx.x;
        if (e < N_EDGES) atomicAdd(&bins[((unsigned)row[e]) >> PSH], 1u);
    }
    __syncthreads();
    for (int i = threadIdx.x; i < NP; i += 256)
        if (bins[i]) atomicAdd(&pcnt[i], bins[i]);
}

// ---------------------------------------------------------------------------
// Kernel 4: scan 391 partition counts -> base[] (exclusive), init cursor[]
// ---------------------------------------------------------------------------
__global__ __launch_bounds__(1024) void part_scan(const unsigned* __restrict__ pcnt,
                                                  unsigned* __restrict__ base,
                                                  unsigned* __restrict__ cursor,
                                                  unsigned* __restrict__ row_ptr) {
    __shared__ unsigned s[1024];
    const int t = threadIdx.x;
    unsigned v = (t < NP) ? pcnt[t] : 0u;
    s[t] = v;
    __syncthreads();
#pragma unroll
    for (int off = 1; off < 1024; off <<= 1) {
        unsigned tv = (t >= off) ? s[t - off] : 0u;
        __syncthreads();
        s[t] += tv;
        __syncthreads();
    }
    if (t < NP) {
        unsigned b = s[t] - v;
        base[t] = b;
        cursor[t] = b;
    }
    if (t == 0) {
        base[NP] = N_EDGES;
        row_ptr[N_NODES] = N_EDGES;
    }
}

// ---------------------------------------------------------------------------
// Kernel 5: partition scatter (two LDS-count passes + one range reservation
// per (block, partition); runs now avg 42 edges = 336B -> fewer partial-line
// writes than the 128-node partitioning)
// ---------------------------------------------------------------------------
__global__ __launch_bounds__(256) void part_scatter(const int* __restrict__ row,
                                                    const int* __restrict__ col,
                                                    const float* __restrict__ val,
                                                    unsigned* __restrict__ cursor,
                                                    uint2* __restrict__ part) {
    __shared__ unsigned bins[NP];
    __shared__ unsigned gb[NP];
    for (int i = threadIdx.x; i < NP; i += 256) bins[i] = 0;
    __syncthreads();
    const int e0 = blockIdx.x * SC_CHUNK;
#pragma unroll 4
    for (int j = 0; j < SC_CHUNK / 256; ++j) {
        int e = e0 + j * 256 + threadIdx.x;
        if (e < N_EDGES) atomicAdd(&bins[((unsigned)row[e]) >> PSH], 1u);
    }
    __syncthreads();
    for (int i = threadIdx.x; i < NP; i += 256) {
        unsigned c = bins[i];
        gb[i] = c ? atomicAdd(&cursor[i], c) : 0u;
        bins[i] = 0;
    }
    __syncthreads();
#pragma unroll 4
    for (int j = 0; j < SC_CHUNK / 256; ++j) {
        int e = e0 + j * 256 + threadIdx.x;
        if (e < N_EDGES) {
            unsigned r = (unsigned)row[e];
            unsigned p = r >> PSH;
            unsigned l = atomicAdd(&bins[p], 1u);
            part[gb[p] + l] = make_uint2(((unsigned)col[e]) | ((r & (PSZ - 1u)) << 17),
                                         __float_as_uint(val[e]));
        }
    }
}

// ---------------------------------------------------------------------------
// Kernel 6: per-partition finalize: LDS stage (71.7KB recs) + per-node scan
// + in-place scatter; emits row_ptr. 2 blocks/CU.
// ---------------------------------------------------------------------------
__global__ __launch_bounds__(256) void part_finalize(const unsigned* __restrict__ base,
                                                     uint2* __restrict__ part,
                                                     unsigned* __restrict__ row_ptr) {
    __shared__ uint2 recs[CAP_LDS];
    __shared__ unsigned ncnt[PSZ], nsc[PSZ], ccur[PSZ];
    const int p = blockIdx.x;
    const int t = threadIdx.x;
    const unsigned b = base[p];
    unsigned cnt = base[p + 1] - b;
    if (cnt > CAP_LDS) cnt = CAP_LDS;   // 8.5-sigma guard, never taken
    ncnt[t] = 0;
    __syncthreads();
    for (unsigned i = t; i < cnt; i += 256) {
        uint2 r = part[b + i];
        recs[i] = r;
        atomicAdd(&ncnt[r.x >> 17], 1u);
    }
    __syncthreads();
    nsc[t] = ncnt[t];
    __syncthreads();
#pragma unroll
    for (int off = 1; off < PSZ; off <<= 1) {
        unsigned tv = (t >= off) ? nsc[t - off] : 0u;
        __syncthreads();
        nsc[t] += tv;
        __syncthreads();
    }
    {
        unsigned ex = nsc[t] - ncnt[t];   // exclusive scan
        ccur[t] = ex;
        int node = p * PSZ + t;
        if (node < N_NODES) row_ptr[node] = b + ex;
    }
    __syncthreads();
    for (unsigned i = t; i < cnt; i += 256) {
        uint2 r = recs[i];
        unsigned pos = atomicAdd(&ccur[r.x >> 17], 1u);
        part[b + pos] = make_uint2(r.x & 0x1FFFFu, r.y);
    }
}

// ---------------------------------------------------------------------------
// Kernel 7: SpMM pull, feature-split across TWO DISPATCHES (fb=0,128).
// Lane l owns feats fb+2l..fb+2l+1. Split-dispatch (a) hard-separates the
// phases temporally and (b) drops the profiler's top-5 visibility cutoff to
// ~106us so hidden kernels surface. Batch 16 retained.
// ---------------------------------------------------------------------------
__global__ __launch_bounds__(256)
void spmm_kernel(const unsigned* __restrict__ row_ptr, const uint2* __restrict__ sorted,
                 const unsigned short* __restrict__ support, const float* __restrict__ bias,
                 float* __restrict__ out, int fb) {
    const int lane = threadIdx.x & 63;
    const int n = blockIdx.x * 4 + (threadIdx.x >> 6);
    const unsigned start = __builtin_amdgcn_readfirstlane(row_ptr[n]);
    const unsigned end   = __builtin_amdgcn_readfirstlane(row_ptr[n + 1]);
    const int fo = fb + lane * 2;
    const unsigned short* sp = support + fo;
    float a0 = 0.f, a1 = 0.f;

    unsigned i = start;
    const unsigned nfull = (end - start) >> 4;
    if (nfull) {
        uint2 e[16];
#pragma unroll
        for (int j = 0; j < 16; ++j) e[j] = sorted[i + j];
        for (unsigned bt = 1; bt < nfull; ++bt) {
            ushort2 s[16];
#pragma unroll
            for (int j = 0; j < 16; ++j) s[j] = *(const ushort2*)(sp + (size_t)e[j].x * FOUT);
            uint2 en[16];
#pragma unroll
            for (int j = 0; j < 16; ++j) en[j] = sorted[i + 16 + j];   // prefetch next batch
#pragma unroll
            for (int j = 0; j < 16; ++j) {
                float v = __uint_as_float(e[j].y);
                a0 += v * bf2f(s[j].x); a1 += v * bf2f(s[j].y);
            }
#pragma unroll
            for (int j = 0; j < 16; ++j) e[j] = en[j];
            i += 16;
        }
        ushort2 s[16];
#pragma unroll
        for (int j = 0; j < 16; ++j) s[j] = *(const ushort2*)(sp + (size_t)e[j].x * FOUT);
#pragma unroll
        for (int j = 0; j < 16; ++j) {
            float v = __uint_as_float(e[j].y);
            a0 += v * bf2f(s[j].x); a1 += v * bf2f(s[j].y);
        }
        i += 16;
    }
    if (end - i >= 8) {
        uint2 e[8];
#pragma unroll
        for (int j = 0; j < 8; ++j) e[j] = sorted[i + j];
        ushort2 s[8];
#pragma unroll
        for (int j = 0; j < 8; ++j) s[j] = *(const ushort2*)(sp + (size_t)e[j].x * FOUT);
#pragma unroll
        for (int j = 0; j < 8; ++j) {
            float v = __uint_as_float(e[j].y);
            a0 += v * bf2f(s[j].x); a1 += v * bf2f(s[j].y);
        }
        i += 8;
    }
    for (; i < end; ++i) {
        uint2 e = sorted[i];
        float v = __uint_as_float(e.y);
        ushort2 s0 = *(const ushort2*)(sp + (size_t)e.x * FOUT);
        a0 += v * bf2f(s0.x); a1 += v * bf2f(s0.y);
    }

    float2 bv = *(const float2*)(bias + fo);
    float2 r;
    r.x = rintf(a0 * 1000.f) * 0.001f + bv.x;
    r.y = rintf(a1 * 1000.f) * 0.001f + bv.y;
    *(float2*)(out + (size_t)n * FOUT + fo) = r;
}

// ---------------------------------------------------------------------------
extern "C" void kernel_launch(void* const* d_in, const int* in_sizes, int n_in,
                              void* d_out, int out_size, void* d_ws, size_t ws_size,
                              hipStream_t stream) {
    (void)in_sizes; (void)n_in; (void)out_size; (void)ws_size;
    const float* X    = (const float*)d_in[0];
    const float* W    = (const float*)d_in[1];
    const float* bias = (const float*)d_in[2];
    const float* eval = (const float*)d_in[3];
    const int*   row  = (const int*)d_in[4];
    const int*   col  = (const int*)d_in[5];
    float* out = (float*)d_out;

    char* p = (char*)d_ws;
    auto take = [&](size_t bytes) {
        char* r = p;
        p += (bytes + 511) & ~(size_t)511;
        return r;
    };
    unsigned short* support = (unsigned short*)take((size_t)N_NODES * FOUT * 2); // 51.2 MB
    unsigned short* Wt      = (unsigned short*)take((size_t)FIN * FOUT * 2);     // 256 KB
    unsigned*       pcnt    = (unsigned*)take((size_t)NP * 4);
    unsigned*       base    = (unsigned*)take((size_t)(NP + 1) * 4);
    unsigned*       cursor  = (unsigned*)take((size_t)NP * 4);
    unsigned*       row_ptr = (unsigned*)take((size_t)(N_NODES + 1) * 4);
    uint2*          part    = (uint2*)take((size_t)N_EDGES * 8 + 1024);          // 25.6 MB + slack

    hipMemsetAsync(pcnt, 0, (size_t)NP * 4, stream);
    prep_weight<<<(FIN * FOUT) / 256, 256, 0, stream>>>(W, Wt);
    gemm_kernel<<<(N_NODES + GEMM_BM - 1) / GEMM_BM, 512, 0, stream>>>(X, Wt, support);
    part_hist<<<(N_EDGES + 8191) / 8192, 256, 0, stream>>>(row, pcnt);
    part_scan<<<1, 1024, 0, stream>>>(pcnt, base, cursor, row_ptr);
    part_scatter<<<(N_EDGES + SC_CHUNK - 1) / SC_CHUNK, 256, 0, stream>>>(row, col, eval, cursor, part);
    part_finalize<<<NP, 256, 0, stream>>>(base, part, row_ptr);
    spmm_kernel<<<N_NODES / 4, 256, 0, stream>>>(row_ptr, part, support, bias, out, 0);
    spmm_kernel<<<N_NODES / 4, 256, 0, stream>>>(row_ptr, part, support, bias, out, 128);
}